// Round 17
// baseline (100.756 us; speedup 1.0000x reference)
//
#include <hip/hip_runtime.h>
#include <hip/hip_bf16.h>

// ---------------- problem constants ----------------------------------------
// B=2, T=2, C=256, heads=8, levels=4, points=4, head_dim=32
// level shapes: (64,64),(32,32),(16,16),(8,8); Bt=4
// rows per level (Bt*HW): 16384, 4096, 1024, 256 ; total NR=21760
#define NR 21760

typedef short short8 __attribute__((ext_vector_type(8)));
typedef float f32x4 __attribute__((ext_vector_type(4)));
typedef float f32x2 __attribute__((ext_vector_type(2)));

__device__ __forceinline__ int level_of_row(int R) {
    if (R < 16384) return 0;
    if (R < 20480) return 1;
    if (R < 21504) return 2;
    return 3;
}

__device__ __forceinline__ unsigned pk2(float a, float b) {
    __hip_bfloat16 x = __float2bfloat16(a), y = __float2bfloat16(b);
    return (unsigned)*(unsigned short*)&x | ((unsigned)*(unsigned short*)&y << 16);
}
__device__ __forceinline__ float lo16(unsigned u) { return __uint_as_float(u << 16); }
__device__ __forceinline__ float hi16(unsigned u) { return __uint_as_float(u & 0xffff0000u); }

// ---------------- K1: unified prep: pack + all weight prep, ONE launch -----
__global__ __launch_bounds__(256) void prep_kernel(const float* __restrict__ f0,
                                                   const float* __restrict__ f1,
                                                   const float* __restrict__ f2,
                                                   const float* __restrict__ f3,
                                                   const float* __restrict__ Wq,
                                                   const float* __restrict__ Wv,
                                                   const float* __restrict__ Woff,
                                                   const float* __restrict__ Wattn,
                                                   const float* __restrict__ Wout,
                                                   const float* __restrict__ bq,
                                                   const float* __restrict__ boff,
                                                   const float* __restrict__ battn,
                                                   __hip_bfloat16* __restrict__ XP,
                                                   __hip_bfloat16* __restrict__ WTvo,
                                                   __hip_bfloat16* __restrict__ WTout,
                                                   float* __restrict__ bias_oa) {
    const int bx = blockIdx.x;
    const int tid = threadIdx.x;
    __shared__ float tile[64][65];

    if (bx < 1360) {
        const float* f; int nj, Wl, rowbase, rel;
        if (bx < 1024)      { f = f0; nj = 128; Wl = 64; rowbase = 0;     rel = bx; }
        else if (bx < 1280) { f = f1; nj = 32;  Wl = 32; rowbase = 16384; rel = bx - 1024; }
        else if (bx < 1344) { f = f2; nj = 8;   Wl = 16; rowbase = 20480; rel = bx - 1280; }
        else                { f = f3; nj = 2;   Wl = 8;  rowbase = 21504; rel = bx - 1344; }
        const int HW = Wl * Wl;
        const int HWT = HW * 2;
        const int j0 = (rel % nj) * 64;
        const int c0 = ((rel / nj) & 3) * 64;
        const int b  = rel / (nj * 4);
        {
            const int cl = tid >> 2, q = tid & 3;
            const float* fb = f + (size_t)(b * 256 + c0 + cl) * HWT + j0 + q * 16;
#pragma unroll
            for (int k = 0; k < 4; ++k) {
                float4 v = *(const float4*)(fb + k * 4);
                *(float4*)(&tile[cl][q * 16 + k * 4]) = v;
            }
        }
        __syncthreads();
        {
            const int jl = tid >> 4, cq = tid & 15;
#pragma unroll
            for (int pass = 0; pass < 4; ++pass) {
                int jloc = pass * 16 + jl;
                int j = j0 + jloc;
                int p = j >> 1, t = j & 1;
                int row = rowbase + (b * 2 + t) * HW + p;
                float v0 = tile[cq * 4 + 0][jloc];
                float v1 = tile[cq * 4 + 1][jloc];
                float v2 = tile[cq * 4 + 2][jloc];
                float v3 = tile[cq * 4 + 3][jloc];
                uint2 o;
                o.x = pk2(v0, v1); o.y = pk2(v2, v3);
                *(uint2*)(&XP[(size_t)row * 256 + c0 + cq * 4]) = o;
            }
        }
        return;
    }
    if (bx == 1584) {
        {
            int n = tid;
            float s = 0.f;
#pragma unroll 8
            for (int j = 0; j < 256; ++j) s += bq[j] * Woff[(size_t)j * 256 + n];
            bias_oa[n] = s + boff[n];
        }
        if (tid < 128) {
            int n = tid;
            float s = 0.f;
#pragma unroll 8
            for (int j = 0; j < 256; ++j) s += bq[j] * Wattn[(size_t)j * 128 + n];
            bias_oa[256 + n] = s + battn[n];
        }
        return;
    }
    if (bx >= 1488) {
        const int rel = bx - 1488;
        const int n0 = (rel % 12) * 32, k0 = (rel / 12) * 32;
        const int n = tid & 31, kt = tid >> 5;
        const int nn = n0 + n;
        float acc[4] = {0.f, 0.f, 0.f, 0.f};
#pragma unroll 8
        for (int j = 0; j < 256; ++j) {
            float wo = (nn < 256) ? Woff[(size_t)j * 256 + nn]
                                  : Wattn[(size_t)j * 128 + nn - 256];
#pragma unroll
            for (int i = 0; i < 4; ++i)
                acc[i] += wo * Wq[(size_t)(k0 + kt * 4 + i) * 256 + j];
        }
#pragma unroll
        for (int i = 0; i < 4; ++i)
            WTvo[(size_t)(256 + nn) * 256 + k0 + kt * 4 + i] = __float2bfloat16(acc[i]);
        return;
    }
    const float* W = (bx < 1424) ? Wv : Wout;
    __hip_bfloat16* WT = (bx < 1424) ? WTvo : WTout;
    const int rel = (bx - 1360) & 63;
    const int n0 = (rel % 8) * 32, k0 = (rel / 8) * 32;
    const int c = tid & 31, r = tid >> 5;
#pragma unroll
    for (int i = 0; i < 4; ++i)
        tile[r + 8 * i][c] = W[(size_t)(k0 + r + 8 * i) * 256 + n0 + c];
    __syncthreads();
#pragma unroll
    for (int i = 0; i < 4; ++i)
        WT[(size_t)(n0 + r + 8 * i) * 256 + k0 + c] = __float2bfloat16(tile[c][r + 8 * i]);
}

// ---------------- K3: 128x64-tile dual-output projection GEMM --------------
__global__ __launch_bounds__(256) void gemm12864_dual(const __hip_bfloat16* __restrict__ A,
                                                      const __hip_bfloat16* __restrict__ BT,
                                                      const float* __restrict__ bias,
                                                      const float* __restrict__ bias2,
                                                      __hip_bfloat16* __restrict__ VAL,
                                                      __hip_bfloat16* __restrict__ OA) {
    __shared__ __align__(16) __hip_bfloat16 As[128][72];
    __shared__ __align__(16) __hip_bfloat16 Bs[64][72];
    const int m0 = blockIdx.x * 128;
    const int n0 = blockIdx.y * 64;
    const int w = threadIdx.x >> 6;
    const int lane = threadIdx.x & 63;
    const int fr = lane & 15;
    const int fq = lane >> 4;
    const int srow = threadIdx.x >> 3;
    const int schunk = threadIdx.x & 7;
    f32x4 acc[2][4] = {};

    for (int kt = 0; kt < 256; kt += 64) {
        __syncthreads();
#pragma unroll
        for (int i = 0; i < 4; ++i) {
            int r = srow + 32 * i;
            float4 va = *(const float4*)(&A[(size_t)(m0 + r) * 256 + kt + schunk * 8]);
            *(float4*)(&As[r][schunk * 8]) = va;
        }
#pragma unroll
        for (int i = 0; i < 2; ++i) {
            int r = srow + 32 * i;
            float4 vb = *(const float4*)(&BT[(size_t)(n0 + r) * 256 + kt + schunk * 8]);
            *(float4*)(&Bs[r][schunk * 8]) = vb;
        }
        __syncthreads();
#pragma unroll
        for (int ks = 0; ks < 2; ++ks) {
            short8 a[2], b[4];
#pragma unroll
            for (int fi = 0; fi < 2; ++fi)
                a[fi] = *(const short8*)(&As[w * 32 + fi * 16 + fr][ks * 32 + fq * 8]);
#pragma unroll
            for (int fj = 0; fj < 4; ++fj)
                b[fj] = *(const short8*)(&Bs[fj * 16 + fr][ks * 32 + fq * 8]);
#pragma unroll
            for (int fi = 0; fi < 2; ++fi)
#pragma unroll
                for (int fj = 0; fj < 4; ++fj)
                    acc[fi][fj] = __builtin_amdgcn_mfma_f32_16x16x32_bf16(
                        a[fi], b[fj], acc[fi][fj], 0, 0, 0);
        }
    }

    if (n0 < 256) {
#pragma unroll
        for (int fj = 0; fj < 4; ++fj) {
            int col = n0 + fj * 16 + fr;
            float bb = bias[col];
#pragma unroll
            for (int fi = 0; fi < 2; ++fi)
#pragma unroll
                for (int r = 0; r < 4; ++r) {
                    int row = m0 + w * 32 + fi * 16 + fq * 4 + r;
                    VAL[(size_t)row * 256 + col] = __float2bfloat16(acc[fi][fj][r] + bb);
                }
        }
    } else {
#pragma unroll
        for (int fj = 0; fj < 4; ++fj) {
            int c2 = n0 - 256 + fj * 16 + fr;
            float bb = bias2[c2];
#pragma unroll
            for (int fi = 0; fi < 2; ++fi)
#pragma unroll
                for (int r = 0; r < 4; ++r) {
                    int row = m0 + w * 32 + fi * 16 + fq * 4 + r;
                    OA[(size_t)row * 384 + c2] = __float2bfloat16(acc[fi][fj][r] + bb);
                }
        }
    }
}

// ---------------- K6: out-proj GEMM, t-paired tile, float2 scatter ---------
__global__ __launch_bounds__(256) void gemm_scatter_kernel(const __hip_bfloat16* __restrict__ A,
                                                           const __hip_bfloat16* __restrict__ BT,
                                                           const float* __restrict__ bias,
                                                           float* __restrict__ out) {
    const int bx = blockIdx.x;
    int l, b, p0;
    if (bx < 256)      { l = 0; b = bx >> 7;          p0 = (bx & 127) * 32; }
    else if (bx < 320) { l = 1; b = (bx - 256) >> 5;  p0 = ((bx - 256) & 31) * 32; }
    else if (bx < 336) { l = 2; b = (bx - 320) >> 3;  p0 = ((bx - 320) & 7) * 32; }
    else               { l = 3; b = (bx - 336) >> 1;  p0 = ((bx - 336) & 1) * 32; }
    const int qbase[4]    = {0, 16384, 20480, 21504};
    const int hwtab[4]    = {4096, 1024, 256, 64};
    const size_t obase[4] = {0, 4194304, 5242880, 5505024};
    const int HW = hwtab[l];
    const int qb = qbase[l];

    __shared__ __align__(16) __hip_bfloat16 As[64][72];
    __shared__ __align__(16) __hip_bfloat16 Bs[64][72];
    const int n0 = blockIdx.y * 64;
    const int w = threadIdx.x >> 6;
    const int lane = threadIdx.x & 63;
    const int wm = (w >> 1) * 32;
    const int wn = (w & 1) * 32;
    const int fr = lane & 15;
    const int fq = lane >> 4;
    const int srow = threadIdx.x >> 3;
    const int schunk = threadIdx.x & 7;
    f32x4 acc[2][2] = {};

    for (int kt = 0; kt < 256; kt += 64) {
        __syncthreads();
#pragma unroll
        for (int i = 0; i < 2; ++i) {
            int m = srow + 32 * i;
            int t = (m >> 4) & 1;
            int pl = (m & 15) | ((m & 32) >> 1);
            int R = qb + (2 * b + t) * HW + p0 + pl;
            float4 va = *(const float4*)(&A[(size_t)R * 256 + kt + schunk * 8]);
            *(float4*)(&As[m][schunk * 8]) = va;
            float4 vb = *(const float4*)(&BT[(size_t)(n0 + m) * 256 + kt + schunk * 8]);
            *(float4*)(&Bs[m][schunk * 8]) = vb;
        }
        __syncthreads();
#pragma unroll
        for (int ks = 0; ks < 2; ++ks) {
            short8 a[2], bfr[2];
#pragma unroll
            for (int fi = 0; fi < 2; ++fi)
                a[fi] = *(const short8*)(&As[wm + fi * 16 + fr][ks * 32 + fq * 8]);
#pragma unroll
            for (int fj = 0; fj < 2; ++fj)
                bfr[fj] = *(const short8*)(&Bs[wn + fj * 16 + fr][ks * 32 + fq * 8]);
#pragma unroll
            for (int fi = 0; fi < 2; ++fi)
#pragma unroll
                for (int fj = 0; fj < 2; ++fj)
                    acc[fi][fj] = __builtin_amdgcn_mfma_f32_16x16x32_bf16(
                        a[fi], bfr[fj], acc[fi][fj], 0, 0, 0);
        }
    }
    const int plbase = fq * 4 + ((wm & 32) >> 1);
#pragma unroll
    for (int fj = 0; fj < 2; ++fj) {
        int col = n0 + wn + fj * 16 + fr;
        float bb = bias[col];
#pragma unroll
        for (int r = 0; r < 4; ++r) {
            int p = p0 + plbase + r;
            size_t addr = obase[l] + (((size_t)b * 256 + col) * HW + p) * 2;
            float2 v;
            v.x = acc[0][fj][r] + bb;
            v.y = acc[1][fj][r] + bb;
            *(float2*)(out + addr) = v;
        }
    }
}

// ---------------- K5: sampling: full-block phase-1, pair-packed taps -------
// Phase 1: 8 threads per (q,h), 2 taps each (per-thread level uniform);
// softmax over 8-lane group via shfl_xor 1,2,4.
// Phase 2: one ds_read_b128 per tap delivers both heads' tap records.
__device__ __forceinline__ void acc8p(f32x2& p0, f32x2& p1, f32x2& p2, f32x2& p3,
                                      uint4 v, float w) {
    f32x2 w2 = {w, w};
    f32x2 v0 = {lo16(v.x), hi16(v.x)};
    f32x2 v1 = {lo16(v.y), hi16(v.y)};
    f32x2 v2 = {lo16(v.z), hi16(v.z)};
    f32x2 v3 = {lo16(v.w), hi16(v.w)};
    p0 += w2 * v0;
    p1 += w2 * v1;
    p2 += w2 * v2;
    p3 += w2 * v3;
}

#define QB 4
__global__ __launch_bounds__(256, 2) void sample_kernel(const __hip_bfloat16* __restrict__ VAL,
                                                        const __hip_bfloat16* __restrict__ OA,
                                                        __hip_bfloat16* __restrict__ SAMP) {
    __shared__ __align__(16) int2 tapp[QB * 512];   // [q][t(16)][c(4)][h4(4)][half(2)] int2
    const int R0 = blockIdx.x * QB;
    const int tid = threadIdx.x;
    const int qbase[4] = {0, 16384, 20480, 21504};
    const int wsh[4]   = {6, 5, 4, 3};
    const int hwsh[4]  = {12, 10, 8, 6};
    const float invwf[4] = {1.f/64.f, 1.f/32.f, 1.f/16.f, 1.f/8.f};

    // ---- phase 1: all 256 threads; 8 per (q,h); 2 taps each ----
    {
        const int qh = tid >> 3, part2 = tid & 7;   // part2: 0..7
        const int q = qh >> 3, h = qh & 7;
        const int h4 = h & 3, half = h >> 2;
        const int R = R0 + q;
        const int lq = level_of_row(R);
        const int r2 = R - qbase[lq];
        const int bt = r2 >> hwsh[lq];
        const int p  = r2 & ((1 << hwsh[lq]) - 1);
        const int pxi = p & ((1 << wsh[lq]) - 1);
        const int pyi = p >> wsh[lq];
        const float refx = (pxi + 0.5f) * invwf[lq];
        const float refy = (pyi + 0.5f) * invwf[lq];
        const __hip_bfloat16* oarow = OA + (size_t)R * 384;
        uint2 po = *(const uint2*)(oarow + h * 32 + part2 * 4);          // 4 bf16 offsets (2 taps)
        unsigned pa = *(const unsigned*)(oarow + 256 + h * 16 + part2 * 2); // 2 bf16 logits
        float a0 = lo16(pa), a1 = hi16(pa);
        // softmax across the 8-lane group (16 taps of this (q,h))
        float m = fmaxf(a0, a1);
        m = fmaxf(m, __shfl_xor(m, 1));
        m = fmaxf(m, __shfl_xor(m, 2));
        m = fmaxf(m, __shfl_xor(m, 4));
        float e0 = __expf(a0 - m), e1 = __expf(a1 - m);
        float s = e0 + e1;
        s += __shfl_xor(s, 1);
        s += __shfl_xor(s, 2);
        s += __shfl_xor(s, 4);
        const float inv = 1.0f / s;
        const int l = part2 >> 1;                 // taps 2p2, 2p2+1 share level
        const int Wl = 1 << wsh[l];
        const float invWf = invwf[l];
        const int base = (qbase[l] + (bt << hwsh[l])) << 8;
        float oxy[4] = { lo16(po.x), hi16(po.x), lo16(po.y), hi16(po.y) };
        float ee[2] = {e0, e1};
#pragma unroll
        for (int i = 0; i < 2; ++i) {
            float ox = oxy[2 * i], oy = oxy[2 * i + 1];
            float aw = ee[i] * inv;
            float lx = fminf(fmaxf(refx + ox * invWf, 0.f), 1.f);
            float ly = fminf(fmaxf(refy + oy * invWf, 0.f), 1.f);
            float px = lx * Wl - 0.5f;
            float py = ly * Wl - 0.5f;
            float x0f = floorf(px), y0f = floorf(py);
            int x0 = (int)x0f, y0 = (int)y0f;
            float wx = px - x0f, wy = py - y0f;
            float vx0 = (x0 >= 0) ? 1.f : 0.f;
            float vx1 = (x0 + 1 <= Wl - 1) ? 1.f : 0.f;
            float vy0 = (y0 >= 0) ? 1.f : 0.f;
            float vy1 = (y0 + 1 <= Wl - 1) ? 1.f : 0.f;
            int x0c = max(x0, 0), x1c = min(x0 + 1, Wl - 1);
            int y0c = max(y0, 0), y1c = min(y0 + 1, Wl - 1);
            int t = part2 * 2 + i;
            int o00 = base + (((y0c << wsh[l]) + x0c) << 8);
            int o10 = base + (((y0c << wsh[l]) + x1c) << 8);
            int o01 = base + (((y1c << wsh[l]) + x0c) << 8);
            int o11 = base + (((y1c << wsh[l]) + x1c) << 8);
            float w00 = aw * (1.f - wx) * (1.f - wy) * vx0 * vy0;
            float w10 = aw * wx * (1.f - wy) * vx1 * vy0;
            float w01 = aw * (1.f - wx) * wy * vx0 * vy1;
            float w11 = aw * wx * wy * vx1 * vy1;
            // int4 slot for (q, t, c, h4); int2 index = slot*2 + half
            int idx0 = (((q * 16 + t) * 4 + 0) * 4 + h4) * 2 + half;
            tapp[idx0]      = make_int2(o00, __float_as_int(w00));
            tapp[idx0 + 8]  = make_int2(o10, __float_as_int(w10));   // c=1
            tapp[idx0 + 16] = make_int2(o01, __float_as_int(w01));   // c=2
            tapp[idx0 + 24] = make_int2(o11, __float_as_int(w11));   // c=3
        }
    }
    __syncthreads();

    // ---- phase 2: one wave per query; one b128 tap read per t ----
    const int wq = tid >> 6, lane = tid & 63;
    const int u = lane >> 2, sub = lane & 3;
    const int c = u & 3, h4 = u >> 2;
    const int R = R0 + wq;
    const __hip_bfloat16* v0base = VAL + h4 * 32 + sub * 8;
    const __hip_bfloat16* v1base = VAL + (h4 + 4) * 32 + sub * 8;
    const int4* tp = (const int4*)&tapp[wq * 512];
    f32x2 pA0 = {0,0}, pA1 = {0,0}, pA2 = {0,0}, pA3 = {0,0};
    f32x2 pB0 = {0,0}, pB1 = {0,0}, pB2 = {0,0}, pB3 = {0,0};
#pragma unroll 2
    for (int t = 0; t < 16; ++t) {
        int4 d = tp[(t * 4 + c) * 4 + h4];   // {off_lo, w_lo, off_hi, w_hi}
        uint4 x0 = *(const uint4*)(v0base + d.x);
        uint4 x1 = *(const uint4*)(v1base + d.z);
        acc8p(pA0, pA1, pA2, pA3, x0, __int_as_float(d.y));
        acc8p(pB0, pB1, pB2, pB3, x1, __int_as_float(d.w));
    }
    // reduce across corners (lanes differ by 4 and 8)
#pragma unroll
    for (int i = 0; i < 2; ++i) {
        pA0[i] += __shfl_xor(pA0[i], 4); pA0[i] += __shfl_xor(pA0[i], 8);
        pA1[i] += __shfl_xor(pA1[i], 4); pA1[i] += __shfl_xor(pA1[i], 8);
        pA2[i] += __shfl_xor(pA2[i], 4); pA2[i] += __shfl_xor(pA2[i], 8);
        pA3[i] += __shfl_xor(pA3[i], 4); pA3[i] += __shfl_xor(pA3[i], 8);
        pB0[i] += __shfl_xor(pB0[i], 4); pB0[i] += __shfl_xor(pB0[i], 8);
        pB1[i] += __shfl_xor(pB1[i], 4); pB1[i] += __shfl_xor(pB1[i], 8);
        pB2[i] += __shfl_xor(pB2[i], 4); pB2[i] += __shfl_xor(pB2[i], 8);
        pB3[i] += __shfl_xor(pB3[i], 4); pB3[i] += __shfl_xor(pB3[i], 8);
    }
    if (c == 0) {
        uint4 o0, o1;
        o0.x = pk2(pA0.x, pA0.y); o0.y = pk2(pA1.x, pA1.y);
        o0.z = pk2(pA2.x, pA2.y); o0.w = pk2(pA3.x, pA3.y);
        o1.x = pk2(pB0.x, pB0.y); o1.y = pk2(pB1.x, pB1.y);
        o1.z = pk2(pB2.x, pB2.y); o1.w = pk2(pB3.x, pB3.y);
        *(uint4*)(&SAMP[(size_t)R * 256 + h4 * 32 + sub * 8]) = o0;
        *(uint4*)(&SAMP[(size_t)R * 256 + (h4 + 4) * 32 + sub * 8]) = o1;
    }
}

// ---------------- launch ---------------------------------------------------
extern "C" void kernel_launch(void* const* d_in, const int* in_sizes, int n_in,
                              void* d_out, int out_size, void* d_ws, size_t ws_size,
                              hipStream_t stream) {
    (void)in_sizes; (void)n_in; (void)out_size; (void)ws_size;
    const float* f0 = (const float*)d_in[0];
    const float* f1 = (const float*)d_in[1];
    const float* f2 = (const float*)d_in[2];
    const float* f3 = (const float*)d_in[3];
    const float* Wq    = (const float*)d_in[4];
    const float* bq    = (const float*)d_in[5];
    const float* Wv    = (const float*)d_in[6];
    const float* bv    = (const float*)d_in[7];
    const float* Woff  = (const float*)d_in[8];
    const float* boff  = (const float*)d_in[9];
    const float* Wattn = (const float*)d_in[10];
    const float* battn = (const float*)d_in[11];
    const float* Wout  = (const float*)d_in[12];
    const float* bout  = (const float*)d_in[13];
    float* out = (float*)d_out;

    char* w = (char*)d_ws;
    __hip_bfloat16* XPb   = (__hip_bfloat16*)w;   w += (size_t)NR * 256 * 2;
    __hip_bfloat16* SAMPb = (__hip_bfloat16*)w;   w += (size_t)NR * 256 * 2;
    __hip_bfloat16* VAL   = (__hip_bfloat16*)w;   w += (size_t)NR * 256 * 2;
    __hip_bfloat16* OA    = (__hip_bfloat16*)w;   w += (size_t)NR * 384 * 2;   // [OFF(256)|ATT(128)] bf16
    __hip_bfloat16* WTvo  = (__hip_bfloat16*)w;   w += 640 * 256 * 2;          // [Wv^T | W'^T]
    __hip_bfloat16* WTout = (__hip_bfloat16*)w;   w += 256 * 256 * 2;
    float* bias_oa = (float*)w;                   w += 384 * 4;

    // K1: unified prep (pack + weight transposes + W' + bias), one launch
    hipLaunchKernelGGL(prep_kernel, dim3(1585), dim3(256), 0, stream,
                       f0, f1, f2, f3, Wq, Wv, Woff, Wattn, Wout, bq, boff, battn,
                       XPb, WTvo, WTout, bias_oa);

    // K3: fused projection (N=640, 128x64 tiles): VAL (bf16) + OA (bf16)
    hipLaunchKernelGGL(gemm12864_dual, dim3(NR / 128, 10), dim3(256), 0, stream,
                       XPb, WTvo, bv, bias_oa, VAL, OA);

    // K5: sampling (full-block phase-1 + pair-packed taps + 16B-lane gather)
    hipLaunchKernelGGL(sample_kernel, dim3(NR / QB), dim3(256), 0, stream, VAL, OA, SAMPb);

    // K6: output projection, t-paired tile, float2 scatter
    hipLaunchKernelGGL(gemm_scatter_kernel, dim3(340, 4), dim3(256), 0, stream,
                       SAMPb, WTout, bout, out);
}

// Round 18
// 98.542 us; speedup vs baseline: 1.0225x; 1.0225x over previous
//
#include <hip/hip_runtime.h>
#include <hip/hip_bf16.h>

// ---------------- problem constants ----------------------------------------
// B=2, T=2, C=256, heads=8, levels=4, points=4, head_dim=32
// level shapes: (64,64),(32,32),(16,16),(8,8); Bt=4
// rows per level (Bt*HW): 16384, 4096, 1024, 256 ; total NR=21760
#define NR 21760

typedef short short8 __attribute__((ext_vector_type(8)));
typedef float f32x4 __attribute__((ext_vector_type(4)));
typedef float f32x2 __attribute__((ext_vector_type(2)));

__device__ __forceinline__ int level_of_row(int R) {
    if (R < 16384) return 0;
    if (R < 20480) return 1;
    if (R < 21504) return 2;
    return 3;
}

__device__ __forceinline__ unsigned pk2(float a, float b) {
    __hip_bfloat16 x = __float2bfloat16(a), y = __float2bfloat16(b);
    return (unsigned)*(unsigned short*)&x | ((unsigned)*(unsigned short*)&y << 16);
}
__device__ __forceinline__ float lo16(unsigned u) { return __uint_as_float(u << 16); }
__device__ __forceinline__ float hi16(unsigned u) { return __uint_as_float(u & 0xffff0000u); }

// ---------------- K1: unified prep: pack + all weight prep, ONE launch -----
__global__ __launch_bounds__(256) void prep_kernel(const float* __restrict__ f0,
                                                   const float* __restrict__ f1,
                                                   const float* __restrict__ f2,
                                                   const float* __restrict__ f3,
                                                   const float* __restrict__ Wq,
                                                   const float* __restrict__ Wv,
                                                   const float* __restrict__ Woff,
                                                   const float* __restrict__ Wattn,
                                                   const float* __restrict__ Wout,
                                                   const float* __restrict__ bq,
                                                   const float* __restrict__ boff,
                                                   const float* __restrict__ battn,
                                                   __hip_bfloat16* __restrict__ XP,
                                                   __hip_bfloat16* __restrict__ WTvo,
                                                   __hip_bfloat16* __restrict__ WTout,
                                                   float* __restrict__ bias_oa) {
    const int bx = blockIdx.x;
    const int tid = threadIdx.x;
    __shared__ float tile[64][65];

    if (bx < 1360) {
        const float* f; int nj, Wl, rowbase, rel;
        if (bx < 1024)      { f = f0; nj = 128; Wl = 64; rowbase = 0;     rel = bx; }
        else if (bx < 1280) { f = f1; nj = 32;  Wl = 32; rowbase = 16384; rel = bx - 1024; }
        else if (bx < 1344) { f = f2; nj = 8;   Wl = 16; rowbase = 20480; rel = bx - 1280; }
        else                { f = f3; nj = 2;   Wl = 8;  rowbase = 21504; rel = bx - 1344; }
        const int HW = Wl * Wl;
        const int HWT = HW * 2;
        const int j0 = (rel % nj) * 64;
        const int c0 = ((rel / nj) & 3) * 64;
        const int b  = rel / (nj * 4);
        {
            const int cl = tid >> 2, q = tid & 3;
            const float* fb = f + (size_t)(b * 256 + c0 + cl) * HWT + j0 + q * 16;
#pragma unroll
            for (int k = 0; k < 4; ++k) {
                float4 v = *(const float4*)(fb + k * 4);
                *(float4*)(&tile[cl][q * 16 + k * 4]) = v;
            }
        }
        __syncthreads();
        {
            const int jl = tid >> 4, cq = tid & 15;
#pragma unroll
            for (int pass = 0; pass < 4; ++pass) {
                int jloc = pass * 16 + jl;
                int j = j0 + jloc;
                int p = j >> 1, t = j & 1;
                int row = rowbase + (b * 2 + t) * HW + p;
                float v0 = tile[cq * 4 + 0][jloc];
                float v1 = tile[cq * 4 + 1][jloc];
                float v2 = tile[cq * 4 + 2][jloc];
                float v3 = tile[cq * 4 + 3][jloc];
                uint2 o;
                o.x = pk2(v0, v1); o.y = pk2(v2, v3);
                *(uint2*)(&XP[(size_t)row * 256 + c0 + cq * 4]) = o;
            }
        }
        return;
    }
    if (bx == 1584) {
        {
            int n = tid;
            float s = 0.f;
#pragma unroll 8
            for (int j = 0; j < 256; ++j) s += bq[j] * Woff[(size_t)j * 256 + n];
            bias_oa[n] = s + boff[n];
        }
        if (tid < 128) {
            int n = tid;
            float s = 0.f;
#pragma unroll 8
            for (int j = 0; j < 256; ++j) s += bq[j] * Wattn[(size_t)j * 128 + n];
            bias_oa[256 + n] = s + battn[n];
        }
        return;
    }
    if (bx >= 1488) {
        const int rel = bx - 1488;
        const int n0 = (rel % 12) * 32, k0 = (rel / 12) * 32;
        const int n = tid & 31, kt = tid >> 5;
        const int nn = n0 + n;
        float acc[4] = {0.f, 0.f, 0.f, 0.f};
#pragma unroll 8
        for (int j = 0; j < 256; ++j) {
            float wo = (nn < 256) ? Woff[(size_t)j * 256 + nn]
                                  : Wattn[(size_t)j * 128 + nn - 256];
#pragma unroll
            for (int i = 0; i < 4; ++i)
                acc[i] += wo * Wq[(size_t)(k0 + kt * 4 + i) * 256 + j];
        }
#pragma unroll
        for (int i = 0; i < 4; ++i)
            WTvo[(size_t)(256 + nn) * 256 + k0 + kt * 4 + i] = __float2bfloat16(acc[i]);
        return;
    }
    const float* W = (bx < 1424) ? Wv : Wout;
    __hip_bfloat16* WT = (bx < 1424) ? WTvo : WTout;
    const int rel = (bx - 1360) & 63;
    const int n0 = (rel % 8) * 32, k0 = (rel / 8) * 32;
    const int c = tid & 31, r = tid >> 5;
#pragma unroll
    for (int i = 0; i < 4; ++i)
        tile[r + 8 * i][c] = W[(size_t)(k0 + r + 8 * i) * 256 + n0 + c];
    __syncthreads();
#pragma unroll
    for (int i = 0; i < 4; ++i)
        WT[(size_t)(n0 + r + 8 * i) * 256 + k0 + c] = __float2bfloat16(tile[c][r + 8 * i]);
}

// ---------------- K3: 128x64-tile dual-output projection GEMM --------------
__global__ __launch_bounds__(256) void gemm12864_dual(const __hip_bfloat16* __restrict__ A,
                                                      const __hip_bfloat16* __restrict__ BT,
                                                      const float* __restrict__ bias,
                                                      const float* __restrict__ bias2,
                                                      __hip_bfloat16* __restrict__ VAL,
                                                      __hip_bfloat16* __restrict__ OA) {
    __shared__ __align__(16) __hip_bfloat16 As[128][72];
    __shared__ __align__(16) __hip_bfloat16 Bs[64][72];
    const int m0 = blockIdx.x * 128;
    const int n0 = blockIdx.y * 64;
    const int w = threadIdx.x >> 6;
    const int lane = threadIdx.x & 63;
    const int fr = lane & 15;
    const int fq = lane >> 4;
    const int srow = threadIdx.x >> 3;
    const int schunk = threadIdx.x & 7;
    f32x4 acc[2][4] = {};

    for (int kt = 0; kt < 256; kt += 64) {
        __syncthreads();
#pragma unroll
        for (int i = 0; i < 4; ++i) {
            int r = srow + 32 * i;
            float4 va = *(const float4*)(&A[(size_t)(m0 + r) * 256 + kt + schunk * 8]);
            *(float4*)(&As[r][schunk * 8]) = va;
        }
#pragma unroll
        for (int i = 0; i < 2; ++i) {
            int r = srow + 32 * i;
            float4 vb = *(const float4*)(&BT[(size_t)(n0 + r) * 256 + kt + schunk * 8]);
            *(float4*)(&Bs[r][schunk * 8]) = vb;
        }
        __syncthreads();
#pragma unroll
        for (int ks = 0; ks < 2; ++ks) {
            short8 a[2], b[4];
#pragma unroll
            for (int fi = 0; fi < 2; ++fi)
                a[fi] = *(const short8*)(&As[w * 32 + fi * 16 + fr][ks * 32 + fq * 8]);
#pragma unroll
            for (int fj = 0; fj < 4; ++fj)
                b[fj] = *(const short8*)(&Bs[fj * 16 + fr][ks * 32 + fq * 8]);
#pragma unroll
            for (int fi = 0; fi < 2; ++fi)
#pragma unroll
                for (int fj = 0; fj < 4; ++fj)
                    acc[fi][fj] = __builtin_amdgcn_mfma_f32_16x16x32_bf16(
                        a[fi], b[fj], acc[fi][fj], 0, 0, 0);
        }
    }

    if (n0 < 256) {
#pragma unroll
        for (int fj = 0; fj < 4; ++fj) {
            int col = n0 + fj * 16 + fr;
            float bb = bias[col];
#pragma unroll
            for (int fi = 0; fi < 2; ++fi)
#pragma unroll
                for (int r = 0; r < 4; ++r) {
                    int row = m0 + w * 32 + fi * 16 + fq * 4 + r;
                    VAL[(size_t)row * 256 + col] = __float2bfloat16(acc[fi][fj][r] + bb);
                }
        }
    } else {
#pragma unroll
        for (int fj = 0; fj < 4; ++fj) {
            int c2 = n0 - 256 + fj * 16 + fr;
            float bb = bias2[c2];
#pragma unroll
            for (int fi = 0; fi < 2; ++fi)
#pragma unroll
                for (int r = 0; r < 4; ++r) {
                    int row = m0 + w * 32 + fi * 16 + fq * 4 + r;
                    OA[(size_t)row * 384 + c2] = __float2bfloat16(acc[fi][fj][r] + bb);
                }
        }
    }
}

// ---------------- K6: out-proj GEMM, t-paired tile, float2 scatter ---------
__global__ __launch_bounds__(256) void gemm_scatter_kernel(const __hip_bfloat16* __restrict__ A,
                                                           const __hip_bfloat16* __restrict__ BT,
                                                           const float* __restrict__ bias,
                                                           float* __restrict__ out) {
    const int bx = blockIdx.x;
    int l, b, p0;
    if (bx < 256)      { l = 0; b = bx >> 7;          p0 = (bx & 127) * 32; }
    else if (bx < 320) { l = 1; b = (bx - 256) >> 5;  p0 = ((bx - 256) & 31) * 32; }
    else if (bx < 336) { l = 2; b = (bx - 320) >> 3;  p0 = ((bx - 320) & 7) * 32; }
    else               { l = 3; b = (bx - 336) >> 1;  p0 = ((bx - 336) & 1) * 32; }
    const int qbase[4]    = {0, 16384, 20480, 21504};
    const int hwtab[4]    = {4096, 1024, 256, 64};
    const size_t obase[4] = {0, 4194304, 5242880, 5505024};
    const int HW = hwtab[l];
    const int qb = qbase[l];

    __shared__ __align__(16) __hip_bfloat16 As[64][72];
    __shared__ __align__(16) __hip_bfloat16 Bs[64][72];
    const int n0 = blockIdx.y * 64;
    const int w = threadIdx.x >> 6;
    const int lane = threadIdx.x & 63;
    const int wm = (w >> 1) * 32;
    const int wn = (w & 1) * 32;
    const int fr = lane & 15;
    const int fq = lane >> 4;
    const int srow = threadIdx.x >> 3;
    const int schunk = threadIdx.x & 7;
    f32x4 acc[2][2] = {};

    for (int kt = 0; kt < 256; kt += 64) {
        __syncthreads();
#pragma unroll
        for (int i = 0; i < 2; ++i) {
            int m = srow + 32 * i;
            int t = (m >> 4) & 1;
            int pl = (m & 15) | ((m & 32) >> 1);
            int R = qb + (2 * b + t) * HW + p0 + pl;
            float4 va = *(const float4*)(&A[(size_t)R * 256 + kt + schunk * 8]);
            *(float4*)(&As[m][schunk * 8]) = va;
            float4 vb = *(const float4*)(&BT[(size_t)(n0 + m) * 256 + kt + schunk * 8]);
            *(float4*)(&Bs[m][schunk * 8]) = vb;
        }
        __syncthreads();
#pragma unroll
        for (int ks = 0; ks < 2; ++ks) {
            short8 a[2], bfr[2];
#pragma unroll
            for (int fi = 0; fi < 2; ++fi)
                a[fi] = *(const short8*)(&As[wm + fi * 16 + fr][ks * 32 + fq * 8]);
#pragma unroll
            for (int fj = 0; fj < 2; ++fj)
                bfr[fj] = *(const short8*)(&Bs[wn + fj * 16 + fr][ks * 32 + fq * 8]);
#pragma unroll
            for (int fi = 0; fi < 2; ++fi)
#pragma unroll
                for (int fj = 0; fj < 2; ++fj)
                    acc[fi][fj] = __builtin_amdgcn_mfma_f32_16x16x32_bf16(
                        a[fi], bfr[fj], acc[fi][fj], 0, 0, 0);
        }
    }
    const int plbase = fq * 4 + ((wm & 32) >> 1);
#pragma unroll
    for (int fj = 0; fj < 2; ++fj) {
        int col = n0 + wn + fj * 16 + fr;
        float bb = bias[col];
#pragma unroll
        for (int r = 0; r < 4; ++r) {
            int p = p0 + plbase + r;
            size_t addr = obase[l] + (((size_t)b * 256 + col) * HW + p) * 2;
            float2 v;
            v.x = acc[0][fj][r] + bb;
            v.y = acc[1][fj][r] + bb;
            *(float2*)(out + addr) = v;
        }
    }
}

// ---------------- K5: sampling: pair-packed taps, b128 tap reads -----------
// (proven R15 configuration: 128-thread phase-1, 4 threads per (q,h))
__device__ __forceinline__ void acc8p(f32x2& p0, f32x2& p1, f32x2& p2, f32x2& p3,
                                      uint4 v, float w) {
    f32x2 w2 = {w, w};
    f32x2 v0 = {lo16(v.x), hi16(v.x)};
    f32x2 v1 = {lo16(v.y), hi16(v.y)};
    f32x2 v2 = {lo16(v.z), hi16(v.z)};
    f32x2 v3 = {lo16(v.w), hi16(v.w)};
    p0 += w2 * v0;
    p1 += w2 * v1;
    p2 += w2 * v2;
    p3 += w2 * v3;
}

#define QB 4
__global__ __launch_bounds__(256, 2) void sample_kernel(const __hip_bfloat16* __restrict__ VAL,
                                                        const __hip_bfloat16* __restrict__ OA,
                                                        __hip_bfloat16* __restrict__ SAMP) {
    __shared__ __align__(16) int2 tapp[QB * 512];   // [q][t(16)][c(4)][h4(4)][half(2)] int2
    const int R0 = blockIdx.x * QB;
    const int tid = threadIdx.x;
    const int qbase[4] = {0, 16384, 20480, 21504};
    const int wsh[4]   = {6, 5, 4, 3};
    const int hwsh[4]  = {12, 10, 8, 6};
    const float invwf[4] = {1.f/64.f, 1.f/32.f, 1.f/16.f, 1.f/8.f};

    // ---- phase 1: per-(q,h) softmax over 16 + tap precompute (128 threads) ----
    if (tid < QB * 32) {
        const int qh = tid >> 2, part = tid & 3;
        const int q = qh >> 3, h = qh & 7;
        const int h4 = h & 3, half = h >> 2;
        const int R = R0 + q;
        const int lq = level_of_row(R);
        const int r2 = R - qbase[lq];
        const int bt = r2 >> hwsh[lq];
        const int p  = r2 & ((1 << hwsh[lq]) - 1);
        const int pxi = p & ((1 << wsh[lq]) - 1);
        const int pyi = p >> wsh[lq];
        const float refx = (pxi + 0.5f) * invwf[lq];
        const float refy = (pyi + 0.5f) * invwf[lq];
        const __hip_bfloat16* oarow = OA + (size_t)R * 384;
        uint4 po = *(const uint4*)(oarow + h * 32 + part * 8);
        uint2 pa = *(const uint2*)(oarow + 256 + h * 16 + part * 4);
        float a0 = lo16(pa.x), a1 = hi16(pa.x), a2 = lo16(pa.y), a3 = hi16(pa.y);
        float m = fmaxf(fmaxf(a0, a1), fmaxf(a2, a3));
        m = fmaxf(m, __shfl_xor(m, 1));
        m = fmaxf(m, __shfl_xor(m, 2));
        float e0 = __expf(a0 - m), e1 = __expf(a1 - m);
        float e2 = __expf(a2 - m), e3 = __expf(a3 - m);
        float s = e0 + e1 + e2 + e3;
        s += __shfl_xor(s, 1);
        s += __shfl_xor(s, 2);
        const float inv = 1.0f / s;
        const int l = part;
        const int Wl = 1 << wsh[l];
        const float invWf = invwf[l];
        const int base = (qbase[l] + (bt << hwsh[l])) << 8;
        float oxy[8] = { lo16(po.x), hi16(po.x), lo16(po.y), hi16(po.y),
                         lo16(po.z), hi16(po.z), lo16(po.w), hi16(po.w) };
        float ee[4] = {e0, e1, e2, e3};
#pragma unroll
        for (int i = 0; i < 4; ++i) {
            float ox = oxy[2 * i], oy = oxy[2 * i + 1];
            float aw = ee[i] * inv;
            float lx = fminf(fmaxf(refx + ox * invWf, 0.f), 1.f);
            float ly = fminf(fmaxf(refy + oy * invWf, 0.f), 1.f);
            float px = lx * Wl - 0.5f;
            float py = ly * Wl - 0.5f;
            float x0f = floorf(px), y0f = floorf(py);
            int x0 = (int)x0f, y0 = (int)y0f;
            float wx = px - x0f, wy = py - y0f;
            float vx0 = (x0 >= 0) ? 1.f : 0.f;
            float vx1 = (x0 + 1 <= Wl - 1) ? 1.f : 0.f;
            float vy0 = (y0 >= 0) ? 1.f : 0.f;
            float vy1 = (y0 + 1 <= Wl - 1) ? 1.f : 0.f;
            int x0c = max(x0, 0), x1c = min(x0 + 1, Wl - 1);
            int y0c = max(y0, 0), y1c = min(y0 + 1, Wl - 1);
            int t = part * 4 + i;
            int o00 = base + (((y0c << wsh[l]) + x0c) << 8);
            int o10 = base + (((y0c << wsh[l]) + x1c) << 8);
            int o01 = base + (((y1c << wsh[l]) + x0c) << 8);
            int o11 = base + (((y1c << wsh[l]) + x1c) << 8);
            float w00 = aw * (1.f - wx) * (1.f - wy) * vx0 * vy0;
            float w10 = aw * wx * (1.f - wy) * vx1 * vy0;
            float w01 = aw * (1.f - wx) * wy * vx0 * vy1;
            float w11 = aw * wx * wy * vx1 * vy1;
            // base int4 index for (q, t, c=0, h4); int2 slot = idx4*2 + half
            int idx0 = (((q * 16 + t) * 4 + 0) * 4 + h4) * 2 + half;
            tapp[idx0]      = make_int2(o00, __float_as_int(w00));
            tapp[idx0 + 8]  = make_int2(o10, __float_as_int(w10));   // c=1: +4 int4 = +8 int2
            tapp[idx0 + 16] = make_int2(o01, __float_as_int(w01));   // c=2
            tapp[idx0 + 24] = make_int2(o11, __float_as_int(w11));   // c=3
        }
    }
    __syncthreads();

    // ---- phase 2: one wave per query; one b128 tap read per t ----
    const int wq = tid >> 6, lane = tid & 63;
    const int u = lane >> 2, sub = lane & 3;
    const int c = u & 3, h4 = u >> 2;
    const int R = R0 + wq;
    const __hip_bfloat16* v0base = VAL + h4 * 32 + sub * 8;
    const __hip_bfloat16* v1base = VAL + (h4 + 4) * 32 + sub * 8;
    const int4* tp = (const int4*)&tapp[wq * 512];
    f32x2 pA0 = {0,0}, pA1 = {0,0}, pA2 = {0,0}, pA3 = {0,0};
    f32x2 pB0 = {0,0}, pB1 = {0,0}, pB2 = {0,0}, pB3 = {0,0};
#pragma unroll 2
    for (int t = 0; t < 16; ++t) {
        int4 d = tp[(t * 4 + c) * 4 + h4];   // {off_lo, w_lo, off_hi, w_hi}
        uint4 x0 = *(const uint4*)(v0base + d.x);
        uint4 x1 = *(const uint4*)(v1base + d.z);
        acc8p(pA0, pA1, pA2, pA3, x0, __int_as_float(d.y));
        acc8p(pB0, pB1, pB2, pB3, x1, __int_as_float(d.w));
    }
    // reduce across corners (lanes differ by 4 and 8)
#pragma unroll
    for (int i = 0; i < 2; ++i) {
        pA0[i] += __shfl_xor(pA0[i], 4); pA0[i] += __shfl_xor(pA0[i], 8);
        pA1[i] += __shfl_xor(pA1[i], 4); pA1[i] += __shfl_xor(pA1[i], 8);
        pA2[i] += __shfl_xor(pA2[i], 4); pA2[i] += __shfl_xor(pA2[i], 8);
        pA3[i] += __shfl_xor(pA3[i], 4); pA3[i] += __shfl_xor(pA3[i], 8);
        pB0[i] += __shfl_xor(pB0[i], 4); pB0[i] += __shfl_xor(pB0[i], 8);
        pB1[i] += __shfl_xor(pB1[i], 4); pB1[i] += __shfl_xor(pB1[i], 8);
        pB2[i] += __shfl_xor(pB2[i], 4); pB2[i] += __shfl_xor(pB2[i], 8);
        pB3[i] += __shfl_xor(pB3[i], 4); pB3[i] += __shfl_xor(pB3[i], 8);
    }
    if (c == 0) {
        uint4 o0, o1;
        o0.x = pk2(pA0.x, pA0.y); o0.y = pk2(pA1.x, pA1.y);
        o0.z = pk2(pA2.x, pA2.y); o0.w = pk2(pA3.x, pA3.y);
        o1.x = pk2(pB0.x, pB0.y); o1.y = pk2(pB1.x, pB1.y);
        o1.z = pk2(pB2.x, pB2.y); o1.w = pk2(pB3.x, pB3.y);
        *(uint4*)(&SAMP[(size_t)R * 256 + h4 * 32 + sub * 8]) = o0;
        *(uint4*)(&SAMP[(size_t)R * 256 + (h4 + 4) * 32 + sub * 8]) = o1;
    }
}

// ---------------- launch ---------------------------------------------------
extern "C" void kernel_launch(void* const* d_in, const int* in_sizes, int n_in,
                              void* d_out, int out_size, void* d_ws, size_t ws_size,
                              hipStream_t stream) {
    (void)in_sizes; (void)n_in; (void)out_size; (void)ws_size;
    const float* f0 = (const float*)d_in[0];
    const float* f1 = (const float*)d_in[1];
    const float* f2 = (const float*)d_in[2];
    const float* f3 = (const float*)d_in[3];
    const float* Wq    = (const float*)d_in[4];
    const float* bq    = (const float*)d_in[5];
    const float* Wv    = (const float*)d_in[6];
    const float* bv    = (const float*)d_in[7];
    const float* Woff  = (const float*)d_in[8];
    const float* boff  = (const float*)d_in[9];
    const float* Wattn = (const float*)d_in[10];
    const float* battn = (const float*)d_in[11];
    const float* Wout  = (const float*)d_in[12];
    const float* bout  = (const float*)d_in[13];
    float* out = (float*)d_out;

    char* w = (char*)d_ws;
    __hip_bfloat16* XPb   = (__hip_bfloat16*)w;   w += (size_t)NR * 256 * 2;
    __hip_bfloat16* SAMPb = (__hip_bfloat16*)w;   w += (size_t)NR * 256 * 2;
    __hip_bfloat16* VAL   = (__hip_bfloat16*)w;   w += (size_t)NR * 256 * 2;
    __hip_bfloat16* OA    = (__hip_bfloat16*)w;   w += (size_t)NR * 384 * 2;   // [OFF(256)|ATT(128)] bf16
    __hip_bfloat16* WTvo  = (__hip_bfloat16*)w;   w += 640 * 256 * 2;          // [Wv^T | W'^T]
    __hip_bfloat16* WTout = (__hip_bfloat16*)w;   w += 256 * 256 * 2;
    float* bias_oa = (float*)w;                   w += 384 * 4;

    // K1: unified prep (pack + weight transposes + W' + bias), one launch
    hipLaunchKernelGGL(prep_kernel, dim3(1585), dim3(256), 0, stream,
                       f0, f1, f2, f3, Wq, Wv, Woff, Wattn, Wout, bq, boff, battn,
                       XPb, WTvo, WTout, bias_oa);

    // K3: fused projection (N=640, 128x64 tiles): VAL (bf16) + OA (bf16)
    hipLaunchKernelGGL(gemm12864_dual, dim3(NR / 128, 10), dim3(256), 0, stream,
                       XPb, WTvo, bv, bias_oa, VAL, OA);

    // K5: sampling (fused softmax + pair-packed taps + 16B-lane gather)
    hipLaunchKernelGGL(sample_kernel, dim3(NR / QB), dim3(256), 0, stream, VAL, OA, SAMPb);

    // K6: output projection, t-paired tile, float2 scatter
    hipLaunchKernelGGL(gemm_scatter_kernel, dim3(340, 4), dim3(256), 0, stream,
                       SAMPb, WTout, bout, out);
}